// Round 8
// baseline (1316.251 us; speedup 1.0000x reference)
//
#include <hip/hip_runtime.h>

#define HID 2048
#define INTER 1408
#define NEXP 14
#define SINTER 2816
#define TTOK 2048
#define BM 192
#define BK 64
#define ABUFSZ (BM * BK * 2)   // 24576 B per A buffer

#define GLU_SH 264   // 44 nt x 6 ms (384 rows), shared first (longer)
#define GLU_RT 308   // 14 e x 22 nt, in-block m-loop
#define DWN_SH 192   // 32 nt x 6 ms (384 rows), K=2816
#define DWN_RT 448   // 14 e x 32 nt, K=1408

typedef short bf16x8 __attribute__((ext_vector_type(8)));
typedef float f32x4 __attribute__((ext_vector_type(4)));
typedef unsigned short u16x8 __attribute__((ext_vector_type(8)));

__device__ __forceinline__ unsigned short f2bf(float f) {
    __bf16 b = (__bf16)f;
    return __builtin_bit_cast(unsigned short, b);
}
__device__ __forceinline__ float bf2f(unsigned short u) {
    unsigned v = (unsigned)u << 16;
    return __builtin_bit_cast(float, v);
}
// XOR swizzle for 128B-stride rows (conflict-free, proven R4/R6)
__device__ __forceinline__ unsigned swz(unsigned b) { return b ^ (((b >> 7) & 7u) << 4); }

__device__ __forceinline__ void gload16(const void* g, void* l) {
    __builtin_amdgcn_global_load_lds((__attribute__((address_space(1))) void*)g,
                                     (__attribute__((address_space(3))) void*)l, 16, 0, 0);
}
__device__ __forceinline__ void bsync() {
    __builtin_amdgcn_sched_barrier(0);
    __builtin_amdgcn_s_barrier();
    __builtin_amdgcn_sched_barrier(0);
}
#define WAIT_VM_(n) asm volatile("s_waitcnt vmcnt(" #n ")" ::: "memory")
#define WAIT_VM(n) WAIT_VM_(n)
#define WAIT_LGKM0 asm volatile("s_waitcnt lgkmcnt(0)" ::: "memory")

#define PACK8(dst, lo, hi) { \
    dst[0]=(short)f2bf(lo.x); dst[1]=(short)f2bf(lo.y); dst[2]=(short)f2bf(lo.z); dst[3]=(short)f2bf(lo.w); \
    dst[4]=(short)f2bf(hi.x); dst[5]=(short)f2bf(hi.y); dst[6]=(short)f2bf(hi.z); dst[7]=(short)f2bf(hi.w); }

__global__ void k_zero(int* cnt) {
    if ((int)threadIdx.x < NEXP) cnt[threadIdx.x] = 0;
}

__global__ __launch_bounds__(256) void k_xcvt(const float* __restrict__ x,
                                              unsigned short* __restrict__ xb) {
    size_t i = ((size_t)blockIdx.x * 256 + threadIdx.x) * 8;
    float4 a = *(const float4*)(x + i);
    float4 b = *(const float4*)(x + i + 4);
    u16x8 v;
    v[0] = f2bf(a.x); v[1] = f2bf(a.y); v[2] = f2bf(a.z); v[3] = f2bf(a.w);
    v[4] = f2bf(b.x); v[5] = f2bf(b.y); v[6] = f2bf(b.z); v[7] = f2bf(b.w);
    *(u16x8*)(xb + i) = v;
}

__global__ __launch_bounds__(256) void k_router(
    const float* __restrict__ x,
    const float* __restrict__ gate_w, const float* __restrict__ cls_w,
    const float* __restrict__ escale, const float* __restrict__ ebias,
    int* __restrict__ cnt, int* __restrict__ etok, float* __restrict__ ew) {
    const int lane = threadIdx.x & 63;
    const int tok = blockIdx.x * 4 + (threadIdx.x >> 6);
    const float* xr = x + (size_t)tok * HID;
    float xv[32];
#pragma unroll
    for (int i = 0; i < 32; i++) xv[i] = xr[lane + 64 * i];

    float sc[NEXP];
    float mx = 0.f;
#pragma unroll
    for (int e = 0; e < NEXP; e++) {
        const float* cw = cls_w + (size_t)e * HID;
        const float* gw = gate_w + (size_t)e * HID;
        float pc = 0.f, pg = 0.f;
#pragma unroll
        for (int i = 0; i < 32; i++) {
            float v = xv[i];
            pc = fmaf(v, cw[lane + 64 * i], pc);
            pg = fmaf(v, gw[lane + 64 * i], pg);
        }
#pragma unroll
        for (int o = 32; o >= 1; o >>= 1) {
            pc += __shfl_xor(pc, o);
            pg += __shfl_xor(pg, o);
        }
        float lg = pc * (pg / (1.f + __expf(-pg)));
        sc[e] = fabsf(lg);
        mx = fmaxf(mx, sc[e]);
    }
    float s = 0.f;
#pragma unroll
    for (int e = 0; e < NEXP; e++) { sc[e] = __expf(sc[e] - mx); s += sc[e]; }
    float inv = 1.f / s;
    int i1 = -1, i2 = -1;
    float b1 = -1e30f, b2 = -1e30f, v1 = 0.f, v2 = 0.f;
#pragma unroll
    for (int e = 0; e < NEXP; e++) {
        float sv = sc[e] * inv;
        float b = sv + ebias[e];
        if (b > b1) { b2 = b1; i2 = i1; v2 = v1; b1 = b; i1 = e; v1 = sv; }
        else if (b > b2) { b2 = b; i2 = e; v2 = sv; }
    }
    if (lane == 0) {
        float w1 = 1.f + v1 * escale[i1];
        float w2 = 1.f + v2 * escale[i2];
        int p1 = atomicAdd(&cnt[i1], 1);
        etok[i1 * TTOK + p1] = tok * 2;     ew[i1 * TTOK + p1] = w1;
        int p2 = atomicAdd(&cnt[i2], 1);
        etok[i2 * TTOK + p2] = tok * 2 + 1; ew[i2 * TTOK + p2] = w2;
    }
}

__global__ void k_offsets(const int* __restrict__ cnt, int* __restrict__ offs) {
    if (threadIdx.x == 0) {
        int a = 0;
        for (int e = 0; e < NEXP; e++) { offs[e] = a; a += cnt[e]; }
    }
}

#define MFMA16(a, b, c) __builtin_amdgcn_mfma_f32_16x16x32_bf16(a, b, c, 0, 0, 0)

// ---- glu iteration body: counted-vmcnt pipeline, A dbuf, B depth-2 reg ping-pong
#define GLU_ITER(kk, CUR, NXT) { \
    bsync(); \
    if ((kk) + 1 < 32) { \
        const int k1 = ((kk) + 1) * BK; \
        _Pragma("unroll") \
        for (int j = 0; j < 3; j++) \
            gload16(srcA[j] + k1, (char*)sA + (NXT) * ABUFSZ + w * 3072 + j * 1024); \
    } \
    __builtin_amdgcn_sched_barrier(0); \
    if ((kk) + 1 < 32) { WAIT_VM(7); } else { WAIT_VM(0); } \
    __builtin_amdgcn_sched_barrier(0); \
    { bf16x8 vg, vu; \
      PACK8(vg, bgl[CUR], bgh[CUR]); \
      PACK8(vu, bul[CUR], buh[CUR]); \
      *(bf16x8*)((char*)sBg + wBo) = vg; \
      *(bf16x8*)((char*)sBu + wBo) = vu; } \
    if ((kk) + 2 < 32) { \
        const int k2 = ((kk) + 2) * BK; \
        bgl[CUR] = *(const float4*)(srcG + k2); bgh[CUR] = *(const float4*)(srcG + k2 + 4); \
        bul[CUR] = *(const float4*)(srcU + k2); buh[CUR] = *(const float4*)(srcU + k2 + 4); \
    } \
    WAIT_LGKM0; \
    bsync(); \
    __builtin_amdgcn_s_setprio(1); \
    { const char* sAc = (const char*)sA + (CUR) * ABUFSZ; \
      _Pragma("unroll") \
      for (int ks = 0; ks < 2; ++ks) { \
        bf16x8 gf0 = *(const bf16x8*)((const char*)sBg + boff[0][ks]); \
        bf16x8 gf1 = *(const bf16x8*)((const char*)sBg + boff[1][ks]); \
        bf16x8 uf0 = *(const bf16x8*)((const char*)sBu + boff[0][ks]); \
        bf16x8 uf1 = *(const bf16x8*)((const char*)sBu + boff[1][ks]); \
        _Pragma("unroll") \
        for (int mi = 0; mi < 3; mi++) { \
            bf16x8 af = *(const bf16x8*)(sAc + aoff[mi][ks]); \
            ag[mi][0] = MFMA16(af, gf0, ag[mi][0]); \
            ag[mi][1] = MFMA16(af, gf1, ag[mi][1]); \
            au[mi][0] = MFMA16(af, uf0, au[mi][0]); \
            au[mi][1] = MFMA16(af, uf1, au[mi][1]); \
        } \
      } } \
    __builtin_amdgcn_s_setprio(0); \
}

// Gate+up GEMM. BM=192, BN=64(G)+64(U), BK=64, 512 thr / 8 waves (4m x 2n).
__global__ __launch_bounds__(512, 4) void k_glu8(
    const unsigned short* __restrict__ xb,
    const float* __restrict__ wg, const float* __restrict__ wu,
    const float* __restrict__ sg, const float* __restrict__ su,
    unsigned short* __restrict__ abuf, unsigned short* __restrict__ hbuf,
    const int* __restrict__ cnt, const int* __restrict__ offs,
    const int* __restrict__ etok) {
    __shared__ alignas(16) unsigned short sA[2][BM * BK];   // 2 x 24 KB
    __shared__ alignas(16) unsigned short sBg[64 * BK];     // 8 KB
    __shared__ alignas(16) unsigned short sBu[64 * BK];     // 8 KB

    const int bx = blockIdx.x, t = threadIdx.x;
    const int lane = t & 63, w = t >> 6;
    const int wm = w >> 1, wn = w & 1;
    const int fr = lane & 15, fo = lane >> 4;

    const bool routed = bx >= GLU_SH;
    int n0, m_start, m_stop, obase, Ntot;
    const float *Bg, *Bu;
    unsigned short* outp;
    const int* etk = nullptr;
    if (routed) {
        int rx = bx - GLU_SH;
        int e = rx / 22; n0 = (rx % 22) * 64;
        int M = cnt[e];
        if (M <= 0) return;
        m_start = 0; m_stop = M; obase = offs[e]; Ntot = INTER;
        Bg = wg + ((size_t)e * INTER + n0) * HID;
        Bu = wu + ((size_t)e * INTER + n0) * HID;
        outp = abuf; etk = etok + e * TTOK;
    } else {
        n0 = (bx / 6) * 64;
        m_start = (bx % 6) * 384; m_stop = min(TTOK, m_start + 384);
        obase = 0; Ntot = SINTER;
        Bg = sg + (size_t)n0 * HID;
        Bu = su + (size_t)n0 * HID;
        outp = hbuf;
    }

    // B staging: thread -> row t>>3 (0..63), 8 floats at (t&7)*8
    const int brow = t >> 3, bc8 = (t & 7) * 8;
    const float* srcG = Bg + (size_t)brow * HID + bc8;
    const float* srcU = Bu + (size_t)brow * HID + bc8;
    const unsigned wBo = swz((unsigned)(brow * 128 + bc8 * 2));

    unsigned aoff[3][2], boff[2][2];
#pragma unroll
    for (int mi = 0; mi < 3; mi++)
#pragma unroll
        for (int ks = 0; ks < 2; ks++)
            aoff[mi][ks] = swz((unsigned)((wm * 48 + mi * 16 + fr) * 128 + ks * 64 + fo * 16));
#pragma unroll
    for (int nj = 0; nj < 2; nj++)
#pragma unroll
        for (int ks = 0; ks < 2; ks++)
            boff[nj][ks] = swz((unsigned)((wn * 32 + nj * 16 + fr) * 128 + ks * 64 + fo * 16));

    // A gload geometry: wave w, issue j covers rows w*24 + j*8 .. +7 (24 % 8 == 0)
    const int arow_off = lane >> 3;
    const int achunk = (lane & 7) ^ arow_off;

    for (int m0 = m_start; m0 < m_stop; m0 += BM) {
        const int rv = min(m_stop - m0, BM);
        const unsigned short* srcA[3];
#pragma unroll
        for (int j = 0; j < 3; j++) {
            int r = w * 24 + j * 8 + arow_off;
            int rr = r < rv ? r : rv - 1;
            int tok = routed ? (etk[m0 + rr] >> 1) : (m0 + rr);
            srcA[j] = xb + (size_t)tok * HID + achunk * 8;
        }

        f32x4 ag[3][2], au[3][2];
#pragma unroll
        for (int mi = 0; mi < 3; mi++)
#pragma unroll
            for (int nj = 0; nj < 2; nj++) { ag[mi][nj] = {0.f,0.f,0.f,0.f}; au[mi][nj] = {0.f,0.f,0.f,0.f}; }

        // prologue: A(0)->buf0; B(0)->slot0, B(1)->slot1
#pragma unroll
        for (int j = 0; j < 3; j++)
            gload16(srcA[j], (char*)sA + w * 3072 + j * 1024);
        float4 bgl[2], bgh[2], bul[2], buh[2];
        bgl[0] = *(const float4*)(srcG);      bgh[0] = *(const float4*)(srcG + 4);
        bul[0] = *(const float4*)(srcU);      buh[0] = *(const float4*)(srcU + 4);
        bgl[1] = *(const float4*)(srcG + BK); bgh[1] = *(const float4*)(srcG + BK + 4);
        bul[1] = *(const float4*)(srcU + BK); buh[1] = *(const float4*)(srcU + BK + 4);

        for (int kk = 0; kk < 32; kk += 2) {
            GLU_ITER(kk, 0, 1);
            GLU_ITER(kk + 1, 1, 0);
        }

        // epilogue: h = silu(g)*u -> stage bf16 [192][64] in buf0 -> coalesced sweep
        char* sH = (char*)sA;   // last MFMA read buf1 (kk=31)
#pragma unroll
        for (int mi = 0; mi < 3; mi++)
#pragma unroll
            for (int jj = 0; jj < 4; jj++) {
                int r = wm * 48 + mi * 16 + fo * 4 + jj;
#pragma unroll
                for (int nj = 0; nj < 2; nj++) {
                    int c = wn * 32 + nj * 16 + fr;
                    float g = ag[mi][nj][jj];
                    float u = au[mi][nj][jj];
                    float h = (g / (1.f + __expf(-g))) * u;
                    *(unsigned short*)(sH + swz((unsigned)(r * 128 + c * 2))) = f2bf(h);
                }
            }
        WAIT_LGKM0;
        bsync();
#pragma unroll
        for (int q = 0; q < 3; q++) {
            int idx = q * 512 + t;
            int r = idx >> 3, c = idx & 7;
            if (r < rv) {
                uint4 v = *(const uint4*)(sH + swz((unsigned)(r * 128 + c * 16)));
                *(uint4*)(outp + (size_t)(obase + m0 + r) * Ntot + n0 + c * 8) = v;
            }
        }
        bsync();
    }
}

// ---- down iteration body
#define DWN_ITER(kk, CUR, NXT) { \
    bsync(); \
    if ((kk) + 1 < KT) { \
        const int k1 = ((kk) + 1) * BK; \
        _Pragma("unroll") \
        for (int j = 0; j < 3; j++) \
            gload16(srcA[j] + k1, (char*)sA + (NXT) * ABUFSZ + w * 3072 + j * 1024); \
    } \
    __builtin_amdgcn_sched_barrier(0); \
    if ((kk) + 1 < KT) { WAIT_VM(5); } else { WAIT_VM(0); } \
    __builtin_amdgcn_sched_barrier(0); \
    { bf16x8 vb; \
      PACK8(vb, bl[CUR], bh[CUR]); \
      *(bf16x8*)((char*)sB + wBo) = vb; } \
    if ((kk) + 2 < KT) { \
        const int k2 = ((kk) + 2) * BK; \
        bl[CUR] = *(const float4*)(srcB + k2); bh[CUR] = *(const float4*)(srcB + k2 + 4); \
    } \
    WAIT_LGKM0; \
    bsync(); \
    __builtin_amdgcn_s_setprio(1); \
    { const char* sAc = (const char*)sA + (CUR) * ABUFSZ; \
      _Pragma("unroll") \
      for (int ks = 0; ks < 2; ++ks) { \
        bf16x8 bf0 = *(const bf16x8*)((const char*)sB + boff[0][ks]); \
        bf16x8 bf1 = *(const bf16x8*)((const char*)sB + boff[1][ks]); \
        _Pragma("unroll") \
        for (int mi = 0; mi < 3; mi++) { \
            bf16x8 af = *(const bf16x8*)(sAc + aoff[mi][ks]); \
            ac[mi][0] = MFMA16(af, bf0, ac[mi][0]); \
            ac[mi][1] = MFMA16(af, bf1, ac[mi][1]); \
        } \
      } } \
    __builtin_amdgcn_s_setprio(0); \
}

// Down GEMM. BM=192, BN=64, BK=64, 512 thr / 8 waves.
__global__ __launch_bounds__(512, 4) void k_down8(
    const unsigned short* __restrict__ abuf, const unsigned short* __restrict__ hbuf,
    const float* __restrict__ wd, const float* __restrict__ sd,
    unsigned short* __restrict__ slots,
    const int* __restrict__ cnt, const int* __restrict__ offs,
    const int* __restrict__ etok, const float* __restrict__ ew) {
    __shared__ alignas(16) unsigned short sA[2][BM * BK];   // 2 x 24 KB
    __shared__ alignas(16) unsigned short sB[64 * BK];      // 8 KB

    const int bx = blockIdx.x, t = threadIdx.x;
    const int lane = t & 63, w = t >> 6;
    const int wm = w >> 1, wn = w & 1;
    const int fr = lane & 15, fo = lane >> 4;

    const bool routed = bx >= DWN_SH;
    int n0, m_start, m_stop, K, KT;
    const float* W;
    const unsigned short* Abuf;
    size_t arow0 = 0;
    const int* etk = nullptr; const float* ewe = nullptr;
    if (routed) {
        int rx = bx - DWN_SH;
        int e = rx / 32; n0 = (rx % 32) * 64;
        int M = cnt[e];
        if (M <= 0) return;
        m_start = 0; m_stop = M;
        K = INTER; KT = INTER / BK;
        W = wd + (size_t)e * HID * INTER + (size_t)n0 * INTER;
        Abuf = abuf; arow0 = offs[e];
        etk = etok + e * TTOK; ewe = ew + e * TTOK;
    } else {
        n0 = (bx / 6) * 64;
        m_start = (bx % 6) * 384; m_stop = min(TTOK, m_start + 384);
        K = SINTER; KT = SINTER / BK;
        W = sd + (size_t)n0 * SINTER;
        Abuf = hbuf;
    }

    const int brow = t >> 3, bc8 = (t & 7) * 8;
    const float* srcB = W + (size_t)brow * K + bc8;
    const unsigned wBo = swz((unsigned)(brow * 128 + bc8 * 2));

    unsigned aoff[3][2], boff[2][2];
#pragma unroll
    for (int mi = 0; mi < 3; mi++)
#pragma unroll
        for (int ks = 0; ks < 2; ks++)
            aoff[mi][ks] = swz((unsigned)((wm * 48 + mi * 16 + fr) * 128 + ks * 64 + fo * 16));
#pragma unroll
    for (int nj = 0; nj < 2; nj++)
#pragma unroll
        for (int ks = 0; ks < 2; ks++)
            boff[nj][ks] = swz((unsigned)((wn * 32 + nj * 16 + fr) * 128 + ks * 64 + fo * 16));

    const int arow_off = lane >> 3;
    const int achunk = (lane & 7) ^ arow_off;

    for (int m0 = m_start; m0 < m_stop; m0 += BM) {
        const int rv = min(m_stop - m0, BM);
        const unsigned short* srcA[3];
#pragma unroll
        for (int j = 0; j < 3; j++) {
            int r = w * 24 + j * 8 + arow_off;
            int rr = r < rv ? r : rv - 1;
            srcA[j] = Abuf + (arow0 + m0 + rr) * (size_t)K + achunk * 8;
        }

        f32x4 ac[3][2];
#pragma unroll
        for (int mi = 0; mi < 3; mi++)
#pragma unroll
            for (int nj = 0; nj < 2; nj++) ac[mi][nj] = {0.f, 0.f, 0.f, 0.f};

#pragma unroll
        for (int j = 0; j < 3; j++)
            gload16(srcA[j], (char*)sA + w * 3072 + j * 1024);
        float4 bl[2], bh[2];
        bl[0] = *(const float4*)(srcB);      bh[0] = *(const float4*)(srcB + 4);
        bl[1] = *(const float4*)(srcB + BK); bh[1] = *(const float4*)(srcB + BK + 4);

        for (int kk = 0; kk < KT; kk += 2) {
            DWN_ITER(kk, 0, 1);
            DWN_ITER(kk + 1, 1, 0);
        }

        // epilogue: scale by combine weight, stage bf16 [192][64] in buf0, sweep
        char* sH = (char*)sA;   // KT even -> last MFMA read buf1
#pragma unroll
        for (int mi = 0; mi < 3; mi++)
#pragma unroll
            for (int jj = 0; jj < 4; jj++) {
                int r = wm * 48 + mi * 16 + fo * 4 + jj;
                float wt = 1.f;
                if (routed) wt = (r < rv) ? ewe[m0 + r] : 0.f;
#pragma unroll
                for (int nj = 0; nj < 2; nj++) {
                    int c = wn * 32 + nj * 16 + fr;
                    *(unsigned short*)(sH + swz((unsigned)(r * 128 + c * 2))) =
                        f2bf(ac[mi][nj][jj] * wt);
                }
            }
        WAIT_LGKM0;
        bsync();
#pragma unroll
        for (int q = 0; q < 3; q++) {
            int idx = q * 512 + t;
            int r = idx >> 3, c = idx & 7;
            if (r < rv) {
                uint4 v = *(const uint4*)(sH + swz((unsigned)(r * 128 + c * 16)));
                int tok, slice;
                if (routed) { int entry = etk[m0 + r]; tok = entry >> 1; slice = entry & 1; }
                else        { tok = m0 + r; slice = 2; }
                *(uint4*)(slots + ((size_t)slice * TTOK + tok) * HID + n0 + c * 8) = v;
            }
        }
        bsync();
    }
}

__global__ __launch_bounds__(256) void k_final(float* __restrict__ out,
                                               const unsigned short* __restrict__ slots) {
    size_t i = ((size_t)blockIdx.x * 256 + threadIdx.x) * 8;
    u16x8 s0 = *(const u16x8*)(slots + i);
    u16x8 s1 = *(const u16x8*)(slots + (size_t)TTOK * HID + i);
    u16x8 s2 = *(const u16x8*)(slots + (size_t)2 * TTOK * HID + i);
    float4 o0, o1;
    o0.x = bf2f(s0[0]) + bf2f(s1[0]) + bf2f(s2[0]);
    o0.y = bf2f(s0[1]) + bf2f(s1[1]) + bf2f(s2[1]);
    o0.z = bf2f(s0[2]) + bf2f(s1[2]) + bf2f(s2[2]);
    o0.w = bf2f(s0[3]) + bf2f(s1[3]) + bf2f(s2[3]);
    o1.x = bf2f(s0[4]) + bf2f(s1[4]) + bf2f(s2[4]);
    o1.y = bf2f(s0[5]) + bf2f(s1[5]) + bf2f(s2[5]);
    o1.z = bf2f(s0[6]) + bf2f(s1[6]) + bf2f(s2[6]);
    o1.w = bf2f(s0[7]) + bf2f(s1[7]) + bf2f(s2[7]);
    *(float4*)(out + i) = o0;
    *(float4*)(out + i + 4) = o1;
}

extern "C" void kernel_launch(void* const* d_in, const int* in_sizes, int n_in,
                              void* d_out, int out_size, void* d_ws, size_t ws_size,
                              hipStream_t stream) {
    const float* x = (const float*)d_in[0];
    const float* gate_w = (const float*)d_in[1];
    const float* cls_w = (const float*)d_in[2];
    const float* escale = (const float*)d_in[3];
    const float* ebias = (const float*)d_in[4];
    const float* wg = (const float*)d_in[5];
    const float* wu = (const float*)d_in[6];
    const float* wd = (const float*)d_in[7];
    const float* sg = (const float*)d_in[8];
    const float* su = (const float*)d_in[9];
    const float* sd = (const float*)d_in[10];
    float* out = (float*)d_out;

    char* ws = (char*)d_ws;
    size_t o = 0;
    auto alloc = [&](size_t bytes) {
        char* p = ws + o;
        o += (bytes + 255) & ~(size_t)255;
        return p;
    };
    unsigned short* xb    = (unsigned short*)alloc((size_t)TTOK * HID * 2);        // 8 MB
    unsigned short* hbuf  = (unsigned short*)alloc((size_t)TTOK * SINTER * 2);     // 11.5 MB
    unsigned short* abuf  = (unsigned short*)alloc((size_t)2 * TTOK * INTER * 2);  // 11.5 MB
    unsigned short* slots = (unsigned short*)alloc((size_t)3 * TTOK * HID * 2);    // 24 MB
    int* cnt              = (int*)alloc(256);
    int* offs             = (int*)alloc(256);
    int* etok             = (int*)alloc((size_t)NEXP * TTOK * 4);
    float* ew             = (float*)alloc((size_t)NEXP * TTOK * 4);

    k_zero<<<1, 64, 0, stream>>>(cnt);
    k_xcvt<<<2048, 256, 0, stream>>>(x, xb);
    k_router<<<512, 256, 0, stream>>>(x, gate_w, cls_w, escale, ebias, cnt, etok, ew);
    k_offsets<<<1, 64, 0, stream>>>(cnt, offs);
    k_glu8<<<GLU_SH + GLU_RT, 512, 0, stream>>>(
        xb, wg, wu, sg, su, abuf, hbuf, cnt, offs, etok);
    k_down8<<<DWN_SH + DWN_RT, 512, 0, stream>>>(
        abuf, hbuf, wd, sd, slots, cnt, offs, etok, ew);
    k_final<<<2048, 256, 0, stream>>>(out, slots);
}

// Round 9
// 713.230 us; speedup vs baseline: 1.8455x; 1.8455x over previous
//
#include <hip/hip_runtime.h>

#define HID 2048
#define INTER 1408
#define NEXP 14
#define SINTER 2816
#define TTOK 2048
#define BM 384
#define BK 64

#define GLU_SH 264   // 44 nt x 6 m-slices (shared first)
#define GLU_RT 308   // 14 e x 22 nt
#define DWN_SH 96    // 16 nt x 6 m-slices
#define DWN_RT 224   // 14 e x 16 nt

typedef short bf16x8 __attribute__((ext_vector_type(8)));
typedef float f32x4 __attribute__((ext_vector_type(4)));
typedef unsigned short u16x8 __attribute__((ext_vector_type(8)));

__device__ __forceinline__ unsigned short f2bf(float f) {
    __bf16 b = (__bf16)f;
    return __builtin_bit_cast(unsigned short, b);
}
__device__ __forceinline__ float bf2f(unsigned short u) {
    unsigned v = (unsigned)u << 16;
    return __builtin_bit_cast(float, v);
}
// XOR swizzle for 128B-stride rows (conflict-free, proven R4/R6)
__device__ __forceinline__ unsigned swz(unsigned b) { return b ^ (((b >> 7) & 7u) << 4); }

__device__ __forceinline__ void gload16(const void* g, void* l) {
    __builtin_amdgcn_global_load_lds((__attribute__((address_space(1))) void*)g,
                                     (__attribute__((address_space(3))) void*)l, 16, 0, 0);
}
__device__ __forceinline__ void bsync() {
    __builtin_amdgcn_sched_barrier(0);
    __builtin_amdgcn_s_barrier();
    __builtin_amdgcn_sched_barrier(0);
}
#define WAIT_LGKM0 asm volatile("s_waitcnt lgkmcnt(0)" ::: "memory")

__global__ void k_zero(int* cnt) {
    if ((int)threadIdx.x < NEXP) cnt[threadIdx.x] = 0;
}

// Router (fused with x->bf16 conversion). One wave per token.
__global__ __launch_bounds__(256) void k_router(
    const float* __restrict__ x,
    const float* __restrict__ gate_w, const float* __restrict__ cls_w,
    const float* __restrict__ escale, const float* __restrict__ ebias,
    int* __restrict__ cnt, int* __restrict__ etok, float* __restrict__ ew,
    unsigned short* __restrict__ xb) {
    const int lane = threadIdx.x & 63;
    const int tok = blockIdx.x * 4 + (threadIdx.x >> 6);
    const float* xr = x + (size_t)tok * HID;
    float xv[32];
#pragma unroll
    for (int i = 0; i < 32; i++) xv[i] = xr[lane + 64 * i];
    // write bf16 copy (coalesced 128B per instruction)
    unsigned short* xbr = xb + (size_t)tok * HID;
#pragma unroll
    for (int i = 0; i < 32; i++) xbr[lane + 64 * i] = f2bf(xv[i]);

    float sc[NEXP];
    float mx = 0.f;
#pragma unroll
    for (int e = 0; e < NEXP; e++) {
        const float* cw = cls_w + (size_t)e * HID;
        const float* gw = gate_w + (size_t)e * HID;
        float pc = 0.f, pg = 0.f;
#pragma unroll
        for (int i = 0; i < 32; i++) {
            float v = xv[i];
            pc = fmaf(v, cw[lane + 64 * i], pc);
            pg = fmaf(v, gw[lane + 64 * i], pg);
        }
#pragma unroll
        for (int o = 32; o >= 1; o >>= 1) {
            pc += __shfl_xor(pc, o);
            pg += __shfl_xor(pg, o);
        }
        float lg = pc * (pg / (1.f + __expf(-pg)));
        sc[e] = fabsf(lg);
        mx = fmaxf(mx, sc[e]);
    }
    float s = 0.f;
#pragma unroll
    for (int e = 0; e < NEXP; e++) { sc[e] = __expf(sc[e] - mx); s += sc[e]; }
    float inv = 1.f / s;
    int i1 = -1, i2 = -1;
    float b1 = -1e30f, b2 = -1e30f, v1 = 0.f, v2 = 0.f;
#pragma unroll
    for (int e = 0; e < NEXP; e++) {
        float sv = sc[e] * inv;
        float b = sv + ebias[e];
        if (b > b1) { b2 = b1; i2 = i1; v2 = v1; b1 = b; i1 = e; v1 = sv; }
        else if (b > b2) { b2 = b; i2 = e; v2 = sv; }
    }
    if (lane == 0) {
        float w1 = 1.f + v1 * escale[i1];
        float w2 = 1.f + v2 * escale[i2];
        int p1 = atomicAdd(&cnt[i1], 1);
        etok[i1 * TTOK + p1] = tok * 2;     ew[i1 * TTOK + p1] = w1;
        int p2 = atomicAdd(&cnt[i2], 1);
        etok[i2 * TTOK + p2] = tok * 2 + 1; ew[i2 * TTOK + p2] = w2;
    }
}

__global__ void k_offsets(const int* __restrict__ cnt, int* __restrict__ offs) {
    if (threadIdx.x == 0) {
        int a = 0;
        for (int e = 0; e < NEXP; e++) { offs[e] = a; a += cnt[e]; }
    }
}

// Gate+up GEMM. BM=384, BN=64(G)+64(U), BK=64, 1024 thr / 16 waves (8m x 2n).
// A: dbuf via global_load_lds, one-iter prefetch. B: fp32->bf16 reg-carried one iter.
__global__ __launch_bounds__(1024, 4) void k_glu9(
    const unsigned short* __restrict__ xb,
    const float* __restrict__ wg, const float* __restrict__ wu,
    const float* __restrict__ sg, const float* __restrict__ su,
    unsigned short* __restrict__ abuf, unsigned short* __restrict__ hbuf,
    const int* __restrict__ cnt, const int* __restrict__ offs,
    const int* __restrict__ etok) {
    __shared__ alignas(16) unsigned short sA[2][BM * BK];   // 2 x 48 KB
    __shared__ alignas(16) unsigned short sBg[64 * BK];     // 8 KB
    __shared__ alignas(16) unsigned short sBu[64 * BK];     // 8 KB

    const int bx = blockIdx.x, t = threadIdx.x;
    const int lane = t & 63, w = t >> 6;
    const int wm = w >> 1, wn = w & 1;
    const int fr = lane & 15, fo = lane >> 4;

    const bool routed = bx >= GLU_SH;
    int n0, m_start, m_stop, obase, Ntot;
    const float *Bg, *Bu;
    unsigned short* outp;
    const int* etk = nullptr;
    if (routed) {
        int rx = bx - GLU_SH;
        int e = rx / 22; n0 = (rx % 22) * 64;
        int M = cnt[e];
        if (M <= 0) return;
        m_start = 0; m_stop = M; obase = offs[e]; Ntot = INTER;
        Bg = wg + ((size_t)e * INTER + n0) * HID;
        Bu = wu + ((size_t)e * INTER + n0) * HID;
        outp = abuf; etk = etok + e * TTOK;
    } else {
        n0 = (bx / 6) * 64;
        m_start = (bx % 6) * BM; m_stop = min(TTOK, m_start + BM);
        obase = 0; Ntot = SINTER;
        Bg = sg + (size_t)n0 * HID;
        Bu = su + (size_t)n0 * HID;
        outp = hbuf;
    }

    const int brow = t >> 4, bc4 = (t & 15) * 4;
    const float* srcG = Bg + (size_t)brow * HID + bc4;
    const float* srcU = Bu + (size_t)brow * HID + bc4;
    const unsigned wBo = swz((unsigned)(brow * 128 + bc4 * 2));

    unsigned aoff[3][2], boff[2][2];
#pragma unroll
    for (int mi = 0; mi < 3; mi++)
#pragma unroll
        for (int ks = 0; ks < 2; ks++)
            aoff[mi][ks] = swz((unsigned)((wm * 48 + mi * 16 + fr) * 128 + ks * 64 + fo * 16));
#pragma unroll
    for (int nj = 0; nj < 2; nj++)
#pragma unroll
        for (int ks = 0; ks < 2; ks++)
            boff[nj][ks] = swz((unsigned)((wn * 32 + nj * 16 + fr) * 128 + ks * 64 + fo * 16));

    const int arow_off = lane >> 3;
    const int achunk = (lane & 7) ^ arow_off;

    for (int m0 = m_start; m0 < m_stop; m0 += BM) {
        const int rv = min(m_stop - m0, BM);
        const unsigned short* srcA[3];
#pragma unroll
        for (int j = 0; j < 3; j++) {
            int r = (w * 3 + j) * 8 + arow_off;
            int rr = r < rv ? r : rv - 1;
            int tok = routed ? (etk[m0 + rr] >> 1) : (m0 + rr);
            srcA[j] = xb + (size_t)tok * HID + achunk * 8;
        }

        f32x4 ag[3][2], au[3][2];
#pragma unroll
        for (int mi = 0; mi < 3; mi++)
#pragma unroll
            for (int nj = 0; nj < 2; nj++) { ag[mi][nj] = {0.f,0.f,0.f,0.f}; au[mi][nj] = {0.f,0.f,0.f,0.f}; }

        // prologue: A(0) -> buf0, B(0) -> regs
#pragma unroll
        for (int j = 0; j < 3; j++)
            gload16(srcA[j], (char*)sA + (w * 3 + j) * 1024);
        float4 gC = *(const float4*)(srcG);
        float4 uC = *(const float4*)(srcU);
        float4 gN, uN;

        for (int kk = 0; kk < HID / BK; ++kk) {
            const int cur = kk & 1;
            bsync();                       // all waves done reading LDS of iter kk-1
            if (kk + 1 < HID / BK) {       // issue prefetch of (kk+1)
                const int k0n = (kk + 1) * BK;
#pragma unroll
                for (int j = 0; j < 3; j++)
                    gload16(srcA[j] + k0n, (char*)sA + (cur ^ 1) * (BM * BK * 2) + (w * 3 + j) * 1024);
                gN = *(const float4*)(srcG + k0n);
                uN = *(const float4*)(srcU + k0n);
            }
            __builtin_amdgcn_sched_barrier(0);
            {   // ds_write B(kk); compiler's auto-wait is counted (keeps prefetch in flight)
                ushort4 vg, vu;
                vg.x = f2bf(gC.x); vg.y = f2bf(gC.y); vg.z = f2bf(gC.z); vg.w = f2bf(gC.w);
                vu.x = f2bf(uC.x); vu.y = f2bf(uC.y); vu.z = f2bf(uC.z); vu.w = f2bf(uC.w);
                *(ushort4*)((char*)sBg + wBo) = vg;
                *(ushort4*)((char*)sBu + wBo) = vu;
            }
            WAIT_LGKM0;
            bsync();                       // A(kk) + B(kk) visible to all waves
            const char* sAc = (const char*)sA + cur * (BM * BK * 2);
#pragma unroll
            for (int ks = 0; ks < 2; ++ks) {
                bf16x8 af[3], gf[2], uf[2];
#pragma unroll
                for (int mi = 0; mi < 3; mi++) af[mi] = *(const bf16x8*)(sAc + aoff[mi][ks]);
#pragma unroll
                for (int nj = 0; nj < 2; nj++) {
                    gf[nj] = *(const bf16x8*)((const char*)sBg + boff[nj][ks]);
                    uf[nj] = *(const bf16x8*)((const char*)sBu + boff[nj][ks]);
                }
#pragma unroll
                for (int mi = 0; mi < 3; mi++)
#pragma unroll
                    for (int nj = 0; nj < 2; nj++) {
                        ag[mi][nj] = __builtin_amdgcn_mfma_f32_16x16x32_bf16(af[mi], gf[nj], ag[mi][nj], 0, 0, 0);
                        au[mi][nj] = __builtin_amdgcn_mfma_f32_16x16x32_bf16(af[mi], uf[nj], au[mi][nj], 0, 0, 0);
                    }
            }
            gC = gN; uC = uN;
        }

        // epilogue: h = silu(g)*u -> stage bf16 [384][64] in buf0 -> coalesced sweep
        char* sH = (char*)sA;              // last MFMA read buf1 (kk=31)
#pragma unroll
        for (int mi = 0; mi < 3; mi++)
#pragma unroll
            for (int jj = 0; jj < 4; jj++) {
                int r = wm * 48 + mi * 16 + fo * 4 + jj;
#pragma unroll
                for (int nj = 0; nj < 2; nj++) {
                    int c = wn * 32 + nj * 16 + fr;
                    float g = ag[mi][nj][jj];
                    float u = au[mi][nj][jj];
                    float h = (g / (1.f + __expf(-g))) * u;
                    *(unsigned short*)(sH + swz((unsigned)(r * 128 + c * 2))) = f2bf(h);
                }
            }
        WAIT_LGKM0;
        bsync();
#pragma unroll
        for (int q = 0; q < 3; q++) {
            int idx = q * 1024 + t;
            int r = idx >> 3, c = idx & 7;
            if (r < rv) {
                uint4 v = *(const uint4*)(sH + swz((unsigned)(r * 128 + c * 16)));
                *(uint4*)(outp + (size_t)(obase + m0 + r) * Ntot + n0 + c * 8) = v;
            }
        }
        bsync();
    }
}

// Down GEMM. BM=384, BN=128, BK=64, 1024 thr / 16 waves (8m x 2n).
__global__ __launch_bounds__(1024, 4) void k_down9(
    const unsigned short* __restrict__ abuf, const unsigned short* __restrict__ hbuf,
    const float* __restrict__ wd, const float* __restrict__ sd,
    unsigned short* __restrict__ slots,
    const int* __restrict__ cnt, const int* __restrict__ offs,
    const int* __restrict__ etok, const float* __restrict__ ew) {
    __shared__ alignas(16) unsigned short sA[2][BM * BK];   // 2 x 48 KB
    __shared__ alignas(16) unsigned short sB[128 * BK];     // 16 KB

    const int bx = blockIdx.x, t = threadIdx.x;
    const int lane = t & 63, w = t >> 6;
    const int wm = w >> 1, wn = w & 1;
    const int fr = lane & 15, fo = lane >> 4;

    const bool routed = bx >= DWN_SH;
    int n0, m_start, m_stop, K, KT;
    const float* W;
    const unsigned short* Abuf;
    size_t arow0 = 0;
    const int* etk = nullptr; const float* ewe = nullptr;
    if (routed) {
        int rx = bx - DWN_SH;
        int e = rx / 16; n0 = (rx % 16) * 128;
        int M = cnt[e];
        if (M <= 0) return;
        m_start = 0; m_stop = M;
        K = INTER; KT = INTER / BK;
        W = wd + (size_t)e * HID * INTER + (size_t)n0 * INTER;
        Abuf = abuf; arow0 = offs[e];
        etk = etok + e * TTOK; ewe = ew + e * TTOK;
    } else {
        n0 = (bx / 6) * 128;
        m_start = (bx % 6) * BM; m_stop = min(TTOK, m_start + BM);
        K = SINTER; KT = SINTER / BK;
        W = sd + (size_t)n0 * SINTER;
        Abuf = hbuf;
    }

    // B staging: thread -> row t>>3 (0..127), 8 floats at (t&7)*8
    const int brow = t >> 3, bc8 = (t & 7) * 8;
    const float* srcB = W + (size_t)brow * K + bc8;
    const unsigned wBo = swz((unsigned)(brow * 128 + bc8 * 2));

    unsigned aoff[3][2], boff[4][2];
#pragma unroll
    for (int mi = 0; mi < 3; mi++)
#pragma unroll
        for (int ks = 0; ks < 2; ks++)
            aoff[mi][ks] = swz((unsigned)((wm * 48 + mi * 16 + fr) * 128 + ks * 64 + fo * 16));
#pragma unroll
    for (int nj = 0; nj < 4; nj++)
#pragma unroll
        for (int ks = 0; ks < 2; ks++)
            boff[nj][ks] = swz((unsigned)((wn * 64 + nj * 16 + fr) * 128 + ks * 64 + fo * 16));

    const int arow_off = lane >> 3;
    const int achunk = (lane & 7) ^ arow_off;

    for (int m0 = m_start; m0 < m_stop; m0 += BM) {
        const int rv = min(m_stop - m0, BM);
        const unsigned short* srcA[3];
#pragma unroll
        for (int j = 0; j < 3; j++) {
            int r = (w * 3 + j) * 8 + arow_off;
            int rr = r < rv ? r : rv - 1;
            srcA[j] = Abuf + (arow0 + m0 + rr) * (size_t)K + achunk * 8;
        }

        f32x4 ac[3][4];
#pragma unroll
        for (int mi = 0; mi < 3; mi++)
#pragma unroll
            for (int nj = 0; nj < 4; nj++) ac[mi][nj] = {0.f, 0.f, 0.f, 0.f};

#pragma unroll
        for (int j = 0; j < 3; j++)
            gload16(srcA[j], (char*)sA + (w * 3 + j) * 1024);
        float4 bC0 = *(const float4*)(srcB), bC1 = *(const float4*)(srcB + 4);
        float4 bN0, bN1;

        for (int kk = 0; kk < KT; ++kk) {
            const int cur = kk & 1;
            bsync();
            if (kk + 1 < KT) {
                const int k0n = (kk + 1) * BK;
#pragma unroll
                for (int j = 0; j < 3; j++)
                    gload16(srcA[j] + k0n, (char*)sA + (cur ^ 1) * (BM * BK * 2) + (w * 3 + j) * 1024);
                bN0 = *(const float4*)(srcB + k0n);
                bN1 = *(const float4*)(srcB + k0n + 4);
            }
            __builtin_amdgcn_sched_barrier(0);
            {
                bf16x8 v;
                v[0]=(short)f2bf(bC0.x); v[1]=(short)f2bf(bC0.y); v[2]=(short)f2bf(bC0.z); v[3]=(short)f2bf(bC0.w);
                v[4]=(short)f2bf(bC1.x); v[5]=(short)f2bf(bC1.y); v[6]=(short)f2bf(bC1.z); v[7]=(short)f2bf(bC1.w);
                *(bf16x8*)((char*)sB + wBo) = v;
            }
            WAIT_LGKM0;
            bsync();
            const char* sAc = (const char*)sA + cur * (BM * BK * 2);
#pragma unroll
            for (int ks = 0; ks < 2; ++ks) {
                bf16x8 af[3], bf[4];
#pragma unroll
                for (int mi = 0; mi < 3; mi++) af[mi] = *(const bf16x8*)(sAc + aoff[mi][ks]);
#pragma unroll
                for (int nj = 0; nj < 4; nj++) bf[nj] = *(const bf16x8*)((const char*)sB + boff[nj][ks]);
#pragma unroll
                for (int mi = 0; mi < 3; mi++)
#pragma unroll
                    for (int nj = 0; nj < 4; nj++)
                        ac[mi][nj] = __builtin_amdgcn_mfma_f32_16x16x32_bf16(af[mi], bf[nj], ac[mi][nj], 0, 0, 0);
            }
            bC0 = bN0; bC1 = bN1;
        }

        // epilogue: two 64-col passes staged into buf0 (KT=22/44, last MFMA read buf1)
        char* sH = (char*)sA;
#pragma unroll
        for (int p = 0; p < 2; p++) {
            if (wn == p) {
#pragma unroll
                for (int mi = 0; mi < 3; mi++)
#pragma unroll
                    for (int jj = 0; jj < 4; jj++) {
                        int r = wm * 48 + mi * 16 + fo * 4 + jj;
                        float wt = 1.f;
                        if (routed) wt = (r < rv) ? ewe[m0 + r] : 0.f;
#pragma unroll
                        for (int nj = 0; nj < 4; nj++) {
                            int c = nj * 16 + fr;
                            *(unsigned short*)(sH + swz((unsigned)(r * 128 + c * 2))) =
                                f2bf(ac[mi][nj][jj] * wt);
                        }
                    }
            }
            WAIT_LGKM0;
            bsync();
#pragma unroll
            for (int q = 0; q < 3; q++) {
                int idx = q * 1024 + t;
                int r = idx >> 3, c = idx & 7;
                if (r < rv) {
                    uint4 v = *(const uint4*)(sH + swz((unsigned)(r * 128 + c * 16)));
                    int tok, slice;
                    if (routed) { int entry = etk[m0 + r]; tok = entry >> 1; slice = entry & 1; }
                    else        { tok = m0 + r; slice = 2; }
                    *(uint4*)(slots + ((size_t)slice * TTOK + tok) * HID + n0 + p * 64 + c * 8) = v;
                }
            }
            bsync();
        }
    }
}

__global__ __launch_bounds__(256) void k_final(float* __restrict__ out,
                                               const unsigned short* __restrict__ slots) {
    size_t i = ((size_t)blockIdx.x * 256 + threadIdx.x) * 8;
    u16x8 s0 = *(const u16x8*)(slots + i);
    u16x8 s1 = *(const u16x8*)(slots + (size_t)TTOK * HID + i);
    u16x8 s2 = *(const u16x8*)(slots + (size_t)2 * TTOK * HID + i);
    float4 o0, o1;
    o0.x = bf2f(s0[0]) + bf2f(s1[0]) + bf2f(s2[0]);
    o0.y = bf2f(s0[1]) + bf2f(s1[1]) + bf2f(s2[1]);
    o0.z = bf2f(s0[2]) + bf2f(s1[2]) + bf2f(s2[2]);
    o0.w = bf2f(s0[3]) + bf2f(s1[3]) + bf2f(s2[3]);
    o1.x = bf2f(s0[4]) + bf2f(s1[4]) + bf2f(s2[4]);
    o1.y = bf2f(s0[5]) + bf2f(s1[5]) + bf2f(s2[5]);
    o1.z = bf2f(s0[6]) + bf2f(s1[6]) + bf2f(s2[6]);
    o1.w = bf2f(s0[7]) + bf2f(s1[7]) + bf2f(s2[7]);
    *(float4*)(out + i) = o0;
    *(float4*)(out + i + 4) = o1;
}

extern "C" void kernel_launch(void* const* d_in, const int* in_sizes, int n_in,
                              void* d_out, int out_size, void* d_ws, size_t ws_size,
                              hipStream_t stream) {
    const float* x = (const float*)d_in[0];
    const float* gate_w = (const float*)d_in[1];
    const float* cls_w = (const float*)d_in[2];
    const float* escale = (const float*)d_in[3];
    const float* ebias = (const float*)d_in[4];
    const float* wg = (const float*)d_in[5];
    const float* wu = (const float*)d_in[6];
    const float* wd = (const float*)d_in[7];
    const float* sg = (const float*)d_in[8];
    const float* su = (const float*)d_in[9];
    const float* sd = (const float*)d_in[10];
    float* out = (float*)d_out;

    char* ws = (char*)d_ws;
    size_t o = 0;
    auto alloc = [&](size_t bytes) {
        char* p = ws + o;
        o += (bytes + 255) & ~(size_t)255;
        return p;
    };
    unsigned short* xb    = (unsigned short*)alloc((size_t)TTOK * HID * 2);        // 8 MB
    unsigned short* hbuf  = (unsigned short*)alloc((size_t)TTOK * SINTER * 2);     // 11.5 MB
    unsigned short* abuf  = (unsigned short*)alloc((size_t)2 * TTOK * INTER * 2);  // 11.5 MB
    unsigned short* slots = (unsigned short*)alloc((size_t)3 * TTOK * HID * 2);    // 24 MB
    int* cnt              = (int*)alloc(256);
    int* offs             = (int*)alloc(256);
    int* etok             = (int*)alloc((size_t)NEXP * TTOK * 4);
    float* ew             = (float*)alloc((size_t)NEXP * TTOK * 4);

    k_zero<<<1, 64, 0, stream>>>(cnt);
    k_router<<<512, 256, 0, stream>>>(x, gate_w, cls_w, escale, ebias, cnt, etok, ew, xb);
    k_offsets<<<1, 64, 0, stream>>>(cnt, offs);
    k_glu9<<<GLU_SH + GLU_RT, 1024, 0, stream>>>(
        xb, wg, wu, sg, su, abuf, hbuf, cnt, offs, etok);
    k_down9<<<DWN_SH + DWN_RT, 1024, 0, stream>>>(
        abuf, hbuf, wd, sd, slots, cnt, offs, etok, ew);
    k_final<<<2048, 256, 0, stream>>>(out, slots);
}